// Round 11
// baseline (2135.450 us; speedup 1.0000x reference)
//
#include <hip/hip_runtime.h>
#include <math.h>

// Problem constants
#define NTOT 32768   // T*B
#define CIN  201
#define S    67      // keypoints (seq len)
#define E    8
#define H    2
#define L    12
#define FF   16
#define OUTC 128
#define KF   536     // S*E
#define WPB  4       // waves (= elements) per block
#define THREADS 256
#define SP   80      // padded seq (5 tiles of 16)
#define NT   5       // 16-tiles along s/t

typedef float    v2f __attribute__((ext_vector_type(2)));
typedef float    v4f __attribute__((ext_vector_type(4)));
typedef _Float16 v2h __attribute__((ext_vector_type(2)));
typedef _Float16 v4h __attribute__((ext_vector_type(4)));
typedef __fp16   v2hf __attribute__((ext_vector_type(2)));

#if __has_builtin(__builtin_amdgcn_exp2f)
#define EXP2F(x) __builtin_amdgcn_exp2f(x)
#else
#define EXP2F(x) exp2f(x)
#endif
#if __has_builtin(__builtin_amdgcn_rcpf)
#define RCPF(x) __builtin_amdgcn_rcpf(x)
#else
#define RCPF(x) (1.0f/(x))
#endif
#if __has_builtin(__builtin_amdgcn_rsqf)
#define RSQF(x) __builtin_amdgcn_rsqf(x)
#else
#define RSQF(x) rsqrtf(x)
#endif

// MFMA wrapper: builtin only exists on the DEVICE compile pass; host needs a stub.
static __device__ __forceinline__ v4f MFMA16(v4h a, v4h b, v4f c) {
#if defined(__HIP_DEVICE_COMPILE__)
    return __builtin_amdgcn_mfma_f32_16x16x16f16(a, b, c, 0, 0, 0);
#else
    (void)a; (void)b;
    return c;
#endif
}

// 0.5 (=1/sqrt(DH)) * log2(e): fold softmax scale + exp->exp2 into q
#define QSCALE 0.7213475204444817f

static __device__ __forceinline__ v2h CVTPK(float a, float b) {
#if __has_builtin(__builtin_amdgcn_cvt_pkrtz)
    union { v2hf f; v2h h; } x;
    x.f = __builtin_amdgcn_cvt_pkrtz(a, b);
    return x.h;
#else
    return (v2h){(_Float16)a, (_Float16)b};
#endif
}

__device__ __forceinline__ v2f sp(float x) { return (v2f){x, x}; }
__device__ __forceinline__ unsigned int h2u(v2h h){ union{v2h h;unsigned int u;}x; x.h=h; return x.u; }
__device__ __forceinline__ v4h ld4h(const uint2* p){ union{uint2 u;v4h h;}x; x.u=*p; return x.h; }
__device__ __forceinline__ v4h zero4h(){ return (v4h){(_Float16)0.f,(_Float16)0.f,(_Float16)0.f,(_Float16)0.f}; }

__device__ __forceinline__ void ln8(float* xr, const float* __restrict__ gg,
                                    const float* __restrict__ bb) {
    float m = 0.f;
    #pragma unroll
    for (int e = 0; e < E; ++e) m += xr[e];
    m *= 0.125f;
    float v = 0.f;
    #pragma unroll
    for (int e = 0; e < E; ++e) { float d = xr[e] - m; v += d * d; }
    v *= 0.125f;
    float rs = RSQF(v + 1e-5f);
    #pragma unroll
    for (int e = 0; e < E; ++e) xr[e] = (xr[e] - m) * rs * gg[e] + bb[e];
}

// Pack per-layer transposed weights into wp[L][512] (f32, output-pair adjacency):
//   [0:192)   qkvt[e][j]  = ipw[l][j][e]   (e<8, j<24)
//   [192:256) aowt[e2][e] = aow[l][e][e2]
//   [256:384) f1t[e][f]   = f1w[l][f][e]   (f<16)
//   [384:512) f2t[f][e]   = f2w[l][e][f]
__global__ void prep_kernel(const float* __restrict__ ipw, const float* __restrict__ aow,
                            const float* __restrict__ f1w, const float* __restrict__ f2w,
                            float* __restrict__ wp)
{
    int idx = blockIdx.x * 256 + threadIdx.x;
    if (idx >= L * 512) return;
    int l = idx >> 9, r = idx & 511;
    float v;
    if (r < 192)      { int e = r / 24, j = r % 24;          v = ipw[l*192 + j*8 + e]; }
    else if (r < 256) { int q = r - 192; int e2 = q / 8, e = q % 8; v = aow[l*64 + e*8 + e2]; }
    else if (r < 384) { int q = r - 256; int e = q / 16, f = q % 16; v = f1w[l*128 + f*8 + e]; }
    else              { int q = r - 384; int f = q / 8,  e = q % 8;  v = f2w[l*128 + e*16 + f]; }
    wp[idx] = v;
}

// Per-row QKV projection (output-pair packed); writes Q(scaled)/K/V^T f16 to LDS.
__device__ __forceinline__ void stage1_row(
    const float* __restrict__ qkvt, const float* __restrict__ bq,
    const float* xr, int r, bool pred,
    uint2 (*Qw)[SP], uint2 (*Kw)[SP], _Float16 (*Vw)[SP])
{
    v2f qkv[12];
    #pragma unroll
    for (int p = 0; p < 12; ++p) {
        v2f a = *(const v2f*)(bq + 2*p);
        #pragma unroll
        for (int e = 0; e < E; ++e) a += sp(xr[e]) * (*(const v2f*)(qkvt + e*24 + 2*p));
        qkv[p] = a;
    }
    if (pred) {
        #pragma unroll
        for (int h = 0; h < H; ++h) {
            uint2 qw, kw;
            qw.x = h2u(CVTPK(qkv[2*h].x * QSCALE, qkv[2*h].y * QSCALE));
            qw.y = h2u(CVTPK(qkv[2*h+1].x * QSCALE, qkv[2*h+1].y * QSCALE));
            kw.x = h2u(CVTPK(qkv[4+2*h].x, qkv[4+2*h].y));
            kw.y = h2u(CVTPK(qkv[5+2*h].x, qkv[5+2*h].y));
            Qw[h][r] = qw;
            Kw[h][r] = kw;
            Vw[h*4+0][r] = (_Float16)qkv[8+2*h].x;
            Vw[h*4+1][r] = (_Float16)qkv[8+2*h].y;
            Vw[h*4+2][r] = (_Float16)qkv[9+2*h].x;
            Vw[h*4+3][r] = (_Float16)qkv[9+2*h].y;
        }
    }
}

// Per-row attn_out + residual + LN1 + FF + residual + LN2 (output-pair packed)
__device__ __forceinline__ void stage3_row(
    const float* __restrict__ WL, const float* __restrict__ ba,
    const float* __restrict__ fb1, const float* __restrict__ fb2,
    const float* __restrict__ g1l, const float* __restrict__ b1l,
    const float* __restrict__ g2l, const float* __restrict__ b2l,
    const float* o8, float* xr)
{
    const float* aowt = WL + 192;
    const float* f1t  = WL + 256;
    const float* f2t  = WL + 384;
    #pragma unroll
    for (int p = 0; p < 4; ++p) {
        v2f a = *(const v2f*)(ba + 2*p);
        #pragma unroll
        for (int e2 = 0; e2 < E; ++e2) a += sp(o8[e2]) * (*(const v2f*)(aowt + e2*8 + 2*p));
        xr[2*p] += a.x; xr[2*p+1] += a.y;
    }
    ln8(xr, g1l, b1l);
    float t1[FF];
    #pragma unroll
    for (int p = 0; p < 8; ++p) {
        v2f a = *(const v2f*)(fb1 + 2*p);
        #pragma unroll
        for (int e = 0; e < E; ++e) a += sp(xr[e]) * (*(const v2f*)(f1t + e*16 + 2*p));
        t1[2*p] = fmaxf(a.x, 0.f); t1[2*p+1] = fmaxf(a.y, 0.f);
    }
    #pragma unroll
    for (int p = 0; p < 4; ++p) {
        v2f a = *(const v2f*)(fb2 + 2*p);
        #pragma unroll
        for (int f = 0; f < FF; ++f) a += sp(t1[f]) * (*(const v2f*)(f2t + f*8 + 2*p));
        xr[2*p] += a.x; xr[2*p+1] += a.y;
    }
    ln8(xr, g2l, b2l);
}

__global__ __launch_bounds__(THREADS, 4)
void enc_kernel(const float* __restrict__ pose,
                const float* __restrict__ ew,  const float* __restrict__ ebias,
                const float* __restrict__ wp,  const float* __restrict__ ipb,
                const float* __restrict__ aob,
                const float* __restrict__ f1b, const float* __restrict__ f2b,
                const float* __restrict__ g1,  const float* __restrict__ b1,
                const float* __restrict__ g2,  const float* __restrict__ b2,
                float* __restrict__ xf)
{
    // Wave-private LDS (no __syncthreads needed anywhere):
    __shared__ uint2 Qs[WPB][H][SP];                       // 4 f16 (q, pre-scaled) per row
    __shared__ uint2 Ks[WPB][H][SP];                       // 4 f16 k per row
    __shared__ __align__(16) _Float16 Vs[WPB][H*4][SP];    // V^T[d][t]
    __shared__ float4 Os[WPB][H][SP];                      // O rows (normalized)

    const int lane = threadIdx.x & 63;
    const int w    = threadIdx.x >> 6;
    const int n    = blockIdx.x * WPB + w;
    const int tq   = lane & 15, quad = lane >> 4;
    const int r1c  = (lane < 3) ? (64 + lane) : 66;   // tail row (clamped)
    const bool tact = (lane < 3);

    // zero K/V pads t=67..79 once (rows never rewritten; Q pads too for tidy exp)
    if (lane < 13) {
        int t = S + lane;
        #pragma unroll
        for (int h = 0; h < H; ++h) {
            Qs[w][h][t] = make_uint2(0u, 0u);
            Ks[w][h][t] = make_uint2(0u, 0u);
        }
        #pragma unroll
        for (int d = 0; d < 8; ++d) Vs[w][d][t] = (_Float16)0.f;
    }

    // ---- embed rows lane and 64+lane ----
    float xr0[E], xr1[E];
    {
        const float* p = pose + (size_t)n * CIN + 3 * lane;
        #pragma unroll
        for (int e = 0; e < E; ++e)
            xr0[e] = ebias[e] + p[0]*ew[e*3+0] + p[1]*ew[e*3+1] + p[2]*ew[e*3+2];
        const float* p1 = pose + (size_t)n * CIN + 3 * r1c;
        #pragma unroll
        for (int e = 0; e < E; ++e)
            xr1[e] = ebias[e] + p1[0]*ew[e*3+0] + p1[1]*ew[e*3+1] + p1[2]*ew[e*3+2];
    }

    #pragma unroll 1
    for (int l = 0; l < L; ++l) {
        const float* WL = wp + l * 512;
        const float* bq = ipb + l * 24;

        stage1_row(WL, bq, xr0, lane, true, Qs[w], Ks[w], Vs[w]);
        stage1_row(WL, bq, xr1, r1c, tact, Qs[w], Ks[w], Vs[w]);

        // ---- attention: S^T = K Q^T (MFMA), exp in regs, O^T = V^T P^T (MFMA) ----
        #pragma unroll 1
        for (int h = 0; h < H; ++h) {
            v4h Ka[NT], Va[NT];
            #pragma unroll
            for (int t = 0; t < NT; ++t) {
                Ka[t] = zero4h();
                if (quad == 0) Ka[t] = ld4h(&Ks[w][h][t*16 + tq]);
                Va[t] = zero4h();
                if (tq < 4) Va[t] = *(const v4h*)&Vs[w][h*4 + tq][t*16 + quad*4];
            }
            #pragma unroll 1
            for (int sg = 0; sg < NT; ++sg) {
                v4h bqf = zero4h();
                if (quad == 0) bqf = ld4h(&Qs[w][h][sg*16 + tq]);
                v4f acc = {0.f, 0.f, 0.f, 0.f};
                const v4f zf = {0.f, 0.f, 0.f, 0.f};
                float lsum = 0.f;
                #pragma unroll
                for (int t = 0; t < NT; ++t) {
                    v4f c = MFMA16(Ka[t], bqf, zf);
                    float e0 = EXP2F(c.x), e1 = EXP2F(c.y);
                    float e2 = EXP2F(c.z), e3 = EXP2F(c.w);
                    lsum += (e0 + e1) + (e2 + e3);
                    union { v2h h2[2]; v4h h4; } pu;
                    pu.h2[0] = CVTPK(e0, e1);
                    pu.h2[1] = CVTPK(e2, e3);
                    acc = MFMA16(Va[t], pu.h4, acc);   // C->B identity relayout
                }
                lsum += __shfl_xor(lsum, 16, 64);
                lsum += __shfl_xor(lsum, 32, 64);
                float inv = RCPF(lsum - 13.0f);        // remove 13 pad e=1 terms
                if (quad == 0)
                    Os[w][h][sg*16 + tq] =
                        make_float4(acc.x*inv, acc.y*inv, acc.z*inv, acc.w*inv);
            }
        }

        // ---- per-row epilogue ----
        {
            float o8[E];
            float4 a = Os[w][0][lane];
            float4 b = Os[w][1][lane];
            o8[0]=a.x; o8[1]=a.y; o8[2]=a.z; o8[3]=a.w;
            o8[4]=b.x; o8[5]=b.y; o8[6]=b.z; o8[7]=b.w;
            stage3_row(WL, aob+l*8, f1b+l*16, f2b+l*8,
                       g1+l*8, b1+l*8, g2+l*8, b2+l*8, o8, xr0);
            float o8b[E];
            float4 a2 = Os[w][0][r1c];
            float4 b2v = Os[w][1][r1c];
            o8b[0]=a2.x; o8b[1]=a2.y; o8b[2]=a2.z; o8b[3]=a2.w;
            o8b[4]=b2v.x; o8b[5]=b2v.y; o8b[6]=b2v.z; o8b[7]=b2v.w;
            stage3_row(WL, aob+l*8, f1b+l*16, f2b+l*8,
                       g1+l*8, b1+l*8, g2+l*8, b2+l*8, o8b, xr1);
        }
    }

    {
        float* dst = xf + (size_t)n * KF + lane * E;
        *(float4*)(dst + 0) = make_float4(xr0[0], xr0[1], xr0[2], xr0[3]);
        *(float4*)(dst + 4) = make_float4(xr0[4], xr0[5], xr0[6], xr0[7]);
        if (tact) {
            float* dst2 = xf + (size_t)n * KF + (64 + lane) * E;
            *(float4*)(dst2 + 0) = make_float4(xr1[0], xr1[1], xr1[2], xr1[3]);
            *(float4*)(dst2 + 4) = make_float4(xr1[4], xr1[5], xr1[6], xr1[7]);
        }
    }
}

// wt[k][c] = ow[c][k]
__global__ void tr_kernel(const float* __restrict__ ow, float* __restrict__ wt)
{
    int i = blockIdx.x * 256 + threadIdx.x;
    if (i < OUTC * KF) {
        int c = i / KF, k = i - c * KF;
        wt[k * OUTC + c] = ow[i];
    }
}

// out = tanh(Xf[32768,536] @ Wt[536,128] + b)
__global__ __launch_bounds__(256, 4)
void out_kernel(const float* __restrict__ xf, const float* __restrict__ wt,
                const float* __restrict__ ob, float* __restrict__ out)
{
    __shared__ float Xs[32][68];
    const int lid = threadIdx.x;
    const int tx  = lid & 31;
    const int ty  = lid >> 5;
    const int n0  = blockIdx.x * 32;

    float acc[4][4] = {};

    #pragma unroll 1
    for (int kc = 0; kc < 9; ++kc) {
        const int kb = kc * 64;
        const int kw = (kc < 8) ? 64 : 24;
        __syncthreads();
        const int nvec = 32 * (kw >> 2);
        for (int i = lid; i < nvec; i += 256) {
            int r = i / (kw >> 2), kq = i - r * (kw >> 2);
            *(float4*)&Xs[r][kq*4] =
                *(const float4*)&xf[(size_t)(n0 + r) * KF + kb + kq*4];
        }
        __syncthreads();
        #pragma unroll 4
        for (int k = 0; k < kw; ++k) {
            float4 w4 = *(const float4*)&wt[(size_t)(kb + k) * OUTC + tx*4];
            #pragma unroll
            for (int i = 0; i < 4; ++i) {
                float x = Xs[ty*4 + i][k];
                acc[i][0] += x*w4.x; acc[i][1] += x*w4.y;
                acc[i][2] += x*w4.z; acc[i][3] += x*w4.w;
            }
        }
    }

    const float4 bb = *(const float4*)&ob[tx*4];
    #pragma unroll
    for (int i = 0; i < 4; ++i) {
        int r = n0 + ty*4 + i;
        float4 v;
        v.x = tanhf(acc[i][0] + bb.x);
        v.y = tanhf(acc[i][1] + bb.y);
        v.z = tanhf(acc[i][2] + bb.z);
        v.w = tanhf(acc[i][3] + bb.w);
        *(float4*)(out + (size_t)r * OUTC + tx*4) = v;
    }
}

extern "C" void kernel_launch(void* const* d_in, const int* in_sizes, int n_in,
                              void* d_out, int out_size, void* d_ws, size_t ws_size,
                              hipStream_t stream) {
    (void)in_sizes; (void)n_in; (void)out_size; (void)ws_size;
    const float* pose = (const float*)d_in[0];
    const float* ew   = (const float*)d_in[1];
    const float* eb   = (const float*)d_in[2];
    const float* ipw  = (const float*)d_in[3];
    const float* ipb  = (const float*)d_in[4];
    const float* aow  = (const float*)d_in[5];
    const float* aob  = (const float*)d_in[6];
    const float* f1w  = (const float*)d_in[7];
    const float* f1b  = (const float*)d_in[8];
    const float* f2w  = (const float*)d_in[9];
    const float* f2b  = (const float*)d_in[10];
    const float* g1   = (const float*)d_in[11];
    const float* b1   = (const float*)d_in[12];
    const float* g2   = (const float*)d_in[13];
    const float* b2   = (const float*)d_in[14];
    const float* ow   = (const float*)d_in[15];
    const float* ob   = (const float*)d_in[16];

    float* xf = (float*)d_ws;                               // 70.25 MB
    float* wt = xf + (size_t)NTOT * KF;                     // 268 KB
    float* wp = wt + (size_t)KF * OUTC;                     // 24 KB

    prep_kernel<<<(L*512 + 255)/256, 256, 0, stream>>>(ipw, aow, f1w, f2w, wp);
    enc_kernel<<<NTOT / WPB, THREADS, 0, stream>>>(pose, ew, eb, wp, ipb, aob,
                                                   f1b, f2b, g1, b1, g2, b2, xf);
    tr_kernel<<<(OUTC*KF + 255)/256, 256, 0, stream>>>(ow, wt);
    out_kernel<<<NTOT / 32, 256, 0, stream>>>(xf, wt, ob, (float*)d_out);
}